// Round 7
// baseline (103.230 us; speedup 1.0000x reference)
//
#include <hip/hip_runtime.h>
#include <hip/hip_bf16.h>
#include <stdint.h>

#define N 8192
#define FIN 128
#define H 64
#define QB2 32                   // query rows per block
#define MB2 128                  // keys per iteration (512B/row granule)
#define KSPLIT 2
#define KLEN (N / KSPLIT)        // 4096 keys per block
#define NIT3 (KLEN / MB2)        // 32 iterations
#define STAGE_BYTES 32768        // K 16KB + V 16KB
#define PSTRIDE 68               // P row stride in ushorts ([16][64] + pad)

typedef __attribute__((ext_vector_type(8))) short short8;
typedef __attribute__((ext_vector_type(4))) float f32x4;

#define MFMA16(a, b, c) __builtin_amdgcn_mfma_f32_16x16x32_bf16(a, b, c, 0, 0, 0)

typedef __attribute__((address_space(1))) const void* gas_p;
typedef __attribute__((address_space(3))) void* las_p;

static __device__ __forceinline__ void load_lds16(const void* g, void* l) {
    // dest is wave-uniform base; HW writes lane i at base + i*16.
    __builtin_amdgcn_global_load_lds((gas_p)g, (las_p)l, 16, 0, 0);
}

static __device__ __forceinline__ unsigned short f2bf(float f) {
    unsigned int u = __float_as_uint(f);
    unsigned int r = (u + 0x7FFFu + ((u >> 16) & 1u)) >> 16;
    return (unsigned short)r;
}

// pack two f32 -> two bf16 in one u32 (lo = a, hi = b)
static __device__ __forceinline__ unsigned int cvt_pk_bf16(float a, float b) {
    unsigned int r;
    asm("v_cvt_pk_bf16_f32 %0, %1, %2" : "=v"(r) : "v"(a), "v"(b));
    return r;
}

// -------- kernel 0: W -> W^T bf16; W2 pre-scaled by log2(e)/8 (K-side only) --------
__global__ __launch_bounds__(256) void wprep_kernel(const float* __restrict__ W1,
                                                    const float* __restrict__ W2,
                                                    unsigned short* __restrict__ W1T,
                                                    unsigned short* __restrict__ W2T) {
    const int i = blockIdx.x * 256 + threadIdx.x;
    const int h = i >> 7, f = i & 127;
    W1T[i] = f2bf(W1[f * H + h]);
    W2T[i] = f2bf(W2[f * H + h] * 0.18033688011112042f);  // log2(e)/8
}

// -------- kernel 1: MFMA projection seq @ W -> Q(=V), K in bf16 --------
__global__ __launch_bounds__(256) void proj_kernel(const float* __restrict__ seq,
                                                   const unsigned short* __restrict__ W1T,
                                                   const unsigned short* __restrict__ W2T,
                                                   unsigned short* __restrict__ Qb,
                                                   unsigned short* __restrict__ Kb) {
    const int tid = threadIdx.x;
    const int w = tid >> 6, lane = tid & 63;
    const int g = lane >> 4, c = lane & 15;
    const int wq = w & 1, ww = w >> 1;
    const int r0 = blockIdx.x * 32 + wq * 16;
    const unsigned short* WT = ww ? W2T : W1T;
    unsigned short* Ob = ww ? Kb : Qb;

    short8 af[4];
#pragma unroll
    for (int kc = 0; kc < 4; ++kc) {
        const float* sp = seq + (size_t)(r0 + c) * FIN + kc * 32 + g * 8;
        const f32x4 s0 = *(const f32x4*)sp;
        const f32x4 s1 = *(const f32x4*)(sp + 4);
        short8 v;
#pragma unroll
        for (int j = 0; j < 4; ++j) {
            v[j] = (short)f2bf(s0[j]);
            v[4 + j] = (short)f2bf(s1[j]);
        }
        af[kc] = v;
    }

    f32x4 oa[4] = {};
#pragma unroll
    for (int kc = 0; kc < 4; ++kc) {
#pragma unroll
        for (int ht = 0; ht < 4; ++ht) {
            const short8 wf = *(const short8*)(WT + (size_t)(ht * 16 + c) * FIN + kc * 32 + g * 8);
            oa[ht] = MFMA16(af[kc], wf, oa[ht]);
        }
    }
#pragma unroll
    for (int ht = 0; ht < 4; ++ht)
#pragma unroll
        for (int r = 0; r < 4; ++r) {
            const int row = r0 + g * 4 + r;
            Ob[(size_t)row * H + ht * 16 + c] = f2bf(oa[ht][r]);
        }
}

// -------- kernel 2: transpose Qb -> QT[64][8192] (= V^T) --------
__global__ __launch_bounds__(256) void tr_kernel(const unsigned short* __restrict__ Qb,
                                                 unsigned short* __restrict__ QT) {
    __shared__ unsigned short t[64][65];
    const int m0 = blockIdx.x * 64;
    const int tid = threadIdx.x;
    for (int i = tid; i < 64 * 64; i += 256) {
        const int m = i >> 6, h = i & 63;
        t[h][m] = Qb[(size_t)(m0 + m) * H + h];
    }
    __syncthreads();
    for (int i = tid; i < 64 * 64; i += 256) {
        const int h = i >> 6, m = i & 63;
        QT[(size_t)h * N + m0 + m] = t[h][m];
    }
}

// -------- kernel 3: flash partials — MB=128 (512B/row granule), KSPLIT=2 --------
// 512 blocks = 2/CU (74.2KB LDS), 8 waves/CU. 4 waves = 2(wq) x 2(wk);
// wave owns 16 q-rows x 64-key slice of the 32x128 tile.
// K/V LDS double-buffer via global_load_lds; bias 1-deep register prefetch.
__global__ __launch_bounds__(256, 2) void flash_kernel(const unsigned short* __restrict__ Qb,
                                                       const unsigned short* __restrict__ Kb,
                                                       const unsigned short* __restrict__ QT,
                                                       const float* __restrict__ bias,
                                                       float* __restrict__ pv,
                                                       float* __restrict__ pd) {
    __shared__ char smem[2 * STAGE_BYTES + 4 * 16 * PSTRIDE * 2];  // 74240 B

    const int tid = threadIdx.x;
    const int w = tid >> 6, lane = tid & 63;
    const int g = lane >> 4, c = lane & 15;
    const int wq = w >> 1, wk = w & 1;
    const int bid = blockIdx.x;
    const int q0 = (bid >> 1) * QB2;
    const int mbase = (bid & 1) * KLEN;

    unsigned short* Pw = (unsigned short*)(smem + 2 * STAGE_BYTES) + w * (16 * PSTRIDE);

    // Q A-fragments for this wave's 16 rows (row=c, k=g*8+j)
    short8 qf0, qf1;
    {
        const unsigned short* qrow = Qb + (size_t)(q0 + wq * 16 + c) * H + g * 8;
        qf0 = *(const short8*)(qrow);
        qf1 = *(const short8*)(qrow + 32);
    }
    const short8 ones = {0x3F80, 0x3F80, 0x3F80, 0x3F80, 0x3F80, 0x3F80, 0x3F80, 0x3F80};

    f32x4 vals[4] = {};   // PV accum; D row=q(g*4+r), col=h(ht*16+c)
    f32x4 vden = {};      // denominator accum

    // stage one 128-key tile (K 16KB + V^T 16KB); 8 global_load_lds per wave
    auto stage = [&](char* sbase, int m0) {
#pragma unroll
        for (int s2 = 0; s2 < 4; ++s2) {
            const int s = w * 4 + s2;          // 0..15
            {   // K: [128 m][64 h] bf16 (128B rows), swz byte ^= (m&7)<<4
                const int m = s * 8 + (lane >> 3);
                const int srcb = ((lane & 7) * 16) ^ ((m & 7) << 4);
                load_lds16((const char*)Kb + (size_t)(mbase + m0 + m) * 128 + srcb,
                           sbase + s * 1024);
            }
            {   // V^T: [64 h][128 m] bf16 (256B rows), swz byte ^= (h&7)<<4
                const int h = s * 4 + (lane >> 4);
                const int srcb = ((lane & 15) * 16) ^ ((h & 7) << 4);
                load_lds16((const char*)QT + (size_t)h * (N * 2) + (size_t)(mbase + m0) * 2 + srcb,
                           sbase + 16384 + s * 1024);
            }
        }
    };

    char* b0 = smem;
    char* b1 = smem + STAGE_BYTES;

    // per-lane bias base: row = q0+wq*16+g*4 (+r), key = mbase+wk*64+c (+it*128+t*16)
    const float* bb = bias + (size_t)(q0 + wq * 16 + g * 4) * N + mbase + wk * 64 + c;

    stage(b0, 0);
    float bcur[16];
#pragma unroll
    for (int t = 0; t < 4; ++t)
#pragma unroll
        for (int r = 0; r < 4; ++r)
            bcur[t * 4 + r] = bb[(size_t)r * N + t * 16];
    __syncthreads();

    for (int it = 0; it < NIT3; ++it) {
        float bnext[16];
        if (it + 1 < NIT3) {
            stage(b1, (it + 1) * MB2);
#pragma unroll
            for (int t = 0; t < 4; ++t)
#pragma unroll
                for (int r = 0; r < 4; ++r)
                    bnext[t * 4 + r] = bb[(size_t)r * N + (it + 1) * MB2 + t * 16];
        }

        const char* kb = b0;
        const char* vb = b0 + 16384;

        // ---- QK^T: 4 column-tiles of 16 keys ----
        f32x4 acc[4];
#pragma unroll
        for (int t = 0; t < 4; ++t) {
            const int m = wk * 64 + t * 16 + c;
            const char* kr = kb + m * 128;
            const int sw = (m & 7) << 4;
            const short8 kf0 = *(const short8*)(kr + ((g * 16) ^ sw));
            const short8 kf1 = *(const short8*)(kr + ((64 + g * 16) ^ sw));
            f32x4 a = {};
            a = MFMA16(qf0, kf0, a);
            a = MFMA16(qf1, kf1, a);
            acc[t] = a;
        }

        // ---- exp2 (K pre-scaled by log2e/8), bias weight, pack to bf16 ----
#pragma unroll
        for (int t = 0; t < 4; t += 2) {
#pragma unroll
            for (int r = 0; r < 4; ++r) {
                const float p0 = exp2f(acc[t][r]) * bcur[t * 4 + r];
                const float p1 = exp2f(acc[t + 1][r]) * bcur[(t + 1) * 4 + r];
                const unsigned int pk = cvt_pk_bf16(p0, p1);
                Pw[(g * 4 + r) * PSTRIDE + t * 16 + c] = (unsigned short)(pk & 0xFFFFu);
                Pw[(g * 4 + r) * PSTRIDE + (t + 1) * 16 + c] = (unsigned short)(pk >> 16);
            }
        }
        __builtin_amdgcn_wave_barrier();

        // ---- PV + denominator: 2 k-slots of 32 keys ----
#pragma unroll
        for (int ks = 0; ks < 2; ++ks) {
            const short8 pa = *(const short8*)(Pw + c * PSTRIDE + ks * 32 + g * 8);
#pragma unroll
            for (int ht = 0; ht < 4; ++ht) {
                const int h = ht * 16 + c;
                const short8 vf = *(const short8*)(vb + h * 256 +
                                                   ((wk * 128 + ks * 64 + g * 16) ^ ((h & 7) << 4)));
                vals[ht] = MFMA16(pa, vf, vals[ht]);
            }
            vden = MFMA16(pa, ones, vden);
        }

        __syncthreads();  // stage(it+1) drained; buffers swap safely
        { char* t0 = b0; b0 = b1; b1 = t0; }
        if (it + 1 < NIT3) {
#pragma unroll
            for (int i = 0; i < 16; ++i) bcur[i] = bnext[i];
        }
    }

    // ---- cross-wk combine; rv (16.6KB) aliases the stage buffers (loop done) ----
    float* rv = (float*)smem;  // [2 wk][32 q][65]
#pragma unroll
    for (int ht = 0; ht < 4; ++ht)
#pragma unroll
        for (int r = 0; r < 4; ++r)
            rv[(wk * 32 + wq * 16 + g * 4 + r) * 65 + ht * 16 + c] = vals[ht][r];
    if (c == 0) {
#pragma unroll
        for (int r = 0; r < 4; ++r)
            rv[(wk * 32 + wq * 16 + g * 4 + r) * 65 + 64] = vden[r];
    }
    __syncthreads();

    const int h = tid & 63;
    for (int qq = tid >> 6; qq < QB2; qq += 4) {
        const float v = rv[qq * 65 + h] + rv[(32 + qq) * 65 + h];
        pv[((size_t)bid * QB2 + qq) * H + h] = v;
        if (h == 0)
            pd[(size_t)bid * QB2 + qq] = rv[qq * 65 + 64] + rv[(32 + qq) * 65 + 64];
    }
}

// -------- kernel 4: combine key-split partials, divide, ELU --------
__global__ __launch_bounds__(256) void reduce_kernel(const float* __restrict__ pv,
                                                     const float* __restrict__ pd,
                                                     float* __restrict__ out) {
    const int i = blockIdx.x * 256 + threadIdx.x;  // N*H
    const int q = i >> 6, h = i & 63;
    const int qc = q >> 5, qi = q & 31;
    float v = 0.f, d = 0.f;
#pragma unroll
    for (int ks = 0; ks < KSPLIT; ++ks) {
        const size_t row = (size_t)(qc * KSPLIT + ks) * QB2 + qi;
        v += pv[row * H + h];
        d += pd[row];
    }
    const float x = v / (d + 1e-19f);
    out[i] = x > 0.f ? x : expm1f(x);
}

extern "C" void kernel_launch(void* const* d_in, const int* in_sizes, int n_in,
                              void* d_out, int out_size, void* d_ws, size_t ws_size,
                              hipStream_t stream) {
    const float* seq  = (const float*)d_in[0];
    const float* bias = (const float*)d_in[1];
    const float* W1   = (const float*)d_in[2];
    const float* W2   = (const float*)d_in[3];
    // d_in[4] = bias_zero (zeros) -- folded out
    float* out = (float*)d_out;

    unsigned short* Qb  = (unsigned short*)d_ws;   // 1 MB (also V)
    unsigned short* Kb  = Qb + (size_t)N * H;      // 1 MB
    unsigned short* QT  = Kb + (size_t)N * H;      // 1 MB (V^T)
    unsigned short* W1T = QT + (size_t)N * H;      // 16 KB
    unsigned short* W2T = W1T + (size_t)H * FIN;   // 16 KB
    float* pv = (float*)(W2T + (size_t)H * FIN);   // 512*32*64 f32 = 4 MB
    float* pd = pv + (size_t)(N / QB2) * KSPLIT * QB2 * H;  // 64 KB

    wprep_kernel<<<32, 256, 0, stream>>>(W1, W2, W1T, W2T);
    proj_kernel<<<N / 32, 256, 0, stream>>>(seq, W1T, W2T, Qb, Kb);
    tr_kernel<<<N / 64, 256, 0, stream>>>(Qb, QT);
    flash_kernel<<<(N / QB2) * KSPLIT, 256, 0, stream>>>(Qb, Kb, QT, bias, pv, pd);
    reduce_kernel<<<(N * H) / 256, 256, 0, stream>>>(pv, pd, out);
}

// Round 10
// 98.085 us; speedup vs baseline: 1.0524x; 1.0524x over previous
//
#include <hip/hip_runtime.h>
#include <hip/hip_bf16.h>
#include <stdint.h>

#define N 8192
#define FIN 128
#define H 64
#define QB2 32                   // query rows per block
#define MB2 64                   // keys per iteration
#define KSPLIT 4
#define KLEN (N / KSPLIT)        // 2048 keys per block
#define NIT3 (KLEN / MB2)        // 32 iterations
#define STAGE_BYTES 16384        // K 8KB + V^T 8KB

typedef __attribute__((ext_vector_type(4))) short s16x4;
typedef __attribute__((ext_vector_type(8))) short short8;
typedef __attribute__((ext_vector_type(4))) float f32x4;

#define MFMA16(a, b, c) __builtin_amdgcn_mfma_f32_16x16x32_bf16(a, b, c, 0, 0, 0)

typedef __attribute__((address_space(1))) const void* gas_p;
typedef __attribute__((address_space(3))) void* las_p;

static __device__ __forceinline__ void load_lds16(const void* g, void* l) {
    // dest is wave-uniform base; HW writes lane i at base + i*16.
    __builtin_amdgcn_global_load_lds((gas_p)g, (las_p)l, 16, 0, 0);
}

static __device__ __forceinline__ unsigned short f2bf(float f) {
    unsigned int u = __float_as_uint(f);
    unsigned int r = (u + 0x7FFFu + ((u >> 16) & 1u)) >> 16;
    return (unsigned short)r;
}

// pack two f32 -> two bf16 in one u32 (lo = a, hi = b)
static __device__ __forceinline__ unsigned int cvt_pk_bf16(float a, float b) {
    unsigned int r;
    asm("v_cvt_pk_bf16_f32 %0, %1, %2" : "=v"(r) : "v"(a), "v"(b));
    return r;
}

// -------- kernel 0: W -> W^T bf16; W2 pre-scaled by log2(e)/8 (K-side only) --------
__global__ __launch_bounds__(256) void wprep_kernel(const float* __restrict__ W1,
                                                    const float* __restrict__ W2,
                                                    unsigned short* __restrict__ W1T,
                                                    unsigned short* __restrict__ W2T) {
    const int i = blockIdx.x * 256 + threadIdx.x;
    const int h = i >> 7, f = i & 127;
    W1T[i] = f2bf(W1[f * H + h]);
    W2T[i] = f2bf(W2[f * H + h] * 0.18033688011112042f);  // log2(e)/8
}

// -------- kernel 1: MFMA projection + fused Q transpose --------
// 256 blocks x 32 rows. Waves 0-1: W1 -> Qb (+ LDS transpose tile);
// waves 2-3: W2 -> Kb. Then all threads store QT[64][N] tile coalesced.
__global__ __launch_bounds__(256) void proj_kernel(const float* __restrict__ seq,
                                                   const unsigned short* __restrict__ W1T,
                                                   const unsigned short* __restrict__ W2T,
                                                   unsigned short* __restrict__ Qb,
                                                   unsigned short* __restrict__ Kb,
                                                   unsigned short* __restrict__ QT) {
    __shared__ unsigned short t2[64][40];  // [h][local row], stride 80B
    const int tid = threadIdx.x;
    const int w = tid >> 6, lane = tid & 63;
    const int g = lane >> 4, c = lane & 15;
    const int wq = w & 1, ww = w >> 1;
    const int r0 = blockIdx.x * 32;
    const int rw = r0 + wq * 16;
    const unsigned short* WT = ww ? W2T : W1T;
    unsigned short* Ob = ww ? Kb : Qb;

    short8 af[4];
#pragma unroll
    for (int kc = 0; kc < 4; ++kc) {
        const float* sp = seq + (size_t)(rw + c) * FIN + kc * 32 + g * 8;
        const f32x4 s0 = *(const f32x4*)sp;
        const f32x4 s1 = *(const f32x4*)(sp + 4);
        short8 v;
#pragma unroll
        for (int j = 0; j < 4; ++j) {
            v[j] = (short)f2bf(s0[j]);
            v[4 + j] = (short)f2bf(s1[j]);
        }
        af[kc] = v;
    }

    f32x4 oa[4] = {};
#pragma unroll
    for (int kc = 0; kc < 4; ++kc) {
#pragma unroll
        for (int ht = 0; ht < 4; ++ht) {
            const short8 wf = *(const short8*)(WT + (size_t)(ht * 16 + c) * FIN + kc * 32 + g * 8);
            oa[ht] = MFMA16(af[kc], wf, oa[ht]);
        }
    }
#pragma unroll
    for (int ht = 0; ht < 4; ++ht)
#pragma unroll
        for (int r = 0; r < 4; ++r) {
            const unsigned short b = f2bf(oa[ht][r]);
            Ob[(size_t)(rw + g * 4 + r) * H + ht * 16 + c] = b;
            if (ww == 0) t2[ht * 16 + c][wq * 16 + g * 4 + r] = b;
        }
    __syncthreads();
    // store QT tile: 64 h-rows x 32 local rows; thread -> (h, 8-row quarter)
    const int h = tid >> 2, part = tid & 3;
    const short8 v = *(const short8*)(&t2[h][part * 8]);
    *(short8*)(QT + (size_t)h * N + r0 + part * 8) = v;
}

// -------- kernel 2: flash partials — swapped QK^T, P fully in-register --------
// 1024 blocks (256 q-chunks x KSPLIT) -> 4 blocks/CU (32KB LDS).
// mfma(K,Q): lane (g,c) owns q-row c with keys {4g+r} (t=0) and {16+4g+r} (t=1).
// No cross-lane P movement: the PV B-fragment is built SLOT-MATCHED, element
// j<4 <- V^T[h][4g+j], j>=4 <- V^T[h][16+4g+j-4] (two ds_read_b64).
__global__ __launch_bounds__(256, 4) void flash_kernel(const unsigned short* __restrict__ Qb,
                                                       const unsigned short* __restrict__ Kb,
                                                       const unsigned short* __restrict__ QT,
                                                       const float* __restrict__ bias,
                                                       float* __restrict__ pv,
                                                       float* __restrict__ pd) {
    __shared__ char smem[2 * STAGE_BYTES];  // 32 KB; epilogue rv aliases this

    const int tid = threadIdx.x;
    const int w = tid >> 6, lane = tid & 63;
    const int g = lane >> 4, c = lane & 15;
    const int wq = w >> 1, wk = w & 1;
    const int bid = blockIdx.x;
    const int q0 = (bid >> 2) * QB2;
    const int mbase = (bid & 3) * KLEN;

    // Q B-fragment (col=q=c, k=h=g*8+j), H=64 -> 2 frags
    short8 qf0, qf1;
    {
        const unsigned short* qrow = Qb + (size_t)(q0 + wq * 16 + c) * H + g * 8;
        qf0 = *(const short8*)(qrow);
        qf1 = *(const short8*)(qrow + 32);
    }

    f32x4 vals[4] = {};   // PV accum; D row=q(g*4+r), col=h(ht*16+c)
    float dsum = 0.f;     // per-lane denominator partial (q-row c)

    // stage one 64-key tile (K 8KB + V^T 8KB); 4 global_load_lds per wave
    auto stage = [&](char* sbase, int m0) {
#pragma unroll
        for (int s2 = 0; s2 < 2; ++s2) {
            const int s = w * 2 + s2;          // 0..7
            {   // K: [64 m][64 h] bf16, swz byte ^= (m&7)<<4
                const int m = s * 8 + (lane >> 3);
                const int srcb = ((lane & 7) * 16) ^ ((m & 7) << 4);
                load_lds16((const char*)Kb + (size_t)(mbase + m0 + m) * 128 + srcb,
                           sbase + s * 1024);
            }
            {   // V^T: [64 h][64 m] bf16, swz byte ^= (h&7)<<4
                const int h = s * 8 + (lane >> 3);
                const int srcb = ((lane & 7) * 16) ^ ((h & 7) << 4);
                load_lds16((const char*)QT + (size_t)h * (N * 2) + (size_t)(mbase + m0) * 2 + srcb,
                           sbase + 8192 + s * 1024);
            }
        }
    };

    char* b0 = smem;
    char* b1 = smem + STAGE_BYTES;

    // bias: lane reads row q=c, 4 consecutive keys per dwordx4 (t=0,1)
    const float* bb = bias + (size_t)(q0 + wq * 16 + c) * N + mbase + wk * 32 + g * 4;

    stage(b0, 0);
    f32x4 bcur0 = *(const f32x4*)(bb);
    f32x4 bcur1 = *(const f32x4*)(bb + 16);
    __syncthreads();

    for (int it = 0; it < NIT3; ++it) {
        f32x4 bn0 = bcur0, bn1 = bcur1;
        if (it + 1 < NIT3) {
            stage(b1, (it + 1) * MB2);
            bn0 = *(const f32x4*)(bb + (it + 1) * MB2);
            bn1 = *(const f32x4*)(bb + (it + 1) * MB2 + 16);
        }

        const char* kb = b0;
        const char* vb = b0 + 8192;

        // K A-fragments: A[row=key][k=h]; key = wk*32 + t*16 + c
        short8 kf[2][2];
#pragma unroll
        for (int t = 0; t < 2; ++t) {
            const int m = wk * 32 + t * 16 + c;
            const char* kr = kb + m * 128;
            const int sw = (m & 7) << 4;
            kf[t][0] = *(const short8*)(kr + ((g * 16) ^ sw));
            kf[t][1] = *(const short8*)(kr + ((64 + g * 16) ^ sw));
        }

        // ---- swapped QK^T: lane (g,c) gets P[key = t*16 + g*4 + r][q = c] ----
        f32x4 acc0 = {}, acc1 = {};
        acc0 = MFMA16(kf[0][0], qf0, acc0);
        acc0 = MFMA16(kf[0][1], qf1, acc0);
        acc1 = MFMA16(kf[1][0], qf0, acc1);
        acc1 = MFMA16(kf[1][1], qf1, acc1);

        // ---- P = exp2(S)*bias (K pre-scaled by log2e/8); all for q-row c ----
        const float p00 = exp2f(acc0[0]) * bcur0[0];
        const float p01 = exp2f(acc0[1]) * bcur0[1];
        const float p02 = exp2f(acc0[2]) * bcur0[2];
        const float p03 = exp2f(acc0[3]) * bcur0[3];
        const float p10 = exp2f(acc1[0]) * bcur1[0];
        const float p11 = exp2f(acc1[1]) * bcur1[1];
        const float p12 = exp2f(acc1[2]) * bcur1[2];
        const float p13 = exp2f(acc1[3]) * bcur1[3];
        dsum += ((p00 + p01) + (p02 + p03)) + ((p10 + p11) + (p12 + p13));

        // A-fragment slots (g,j): j=0..3 -> keys 4g+j (t=0); j=4..7 -> 16+4g+(j-4)
        union { unsigned u[4]; short8 s; } pau;
        pau.u[0] = cvt_pk_bf16(p00, p01);
        pau.u[1] = cvt_pk_bf16(p02, p03);
        pau.u[2] = cvt_pk_bf16(p10, p11);
        pau.u[3] = cvt_pk_bf16(p12, p13);

        // ---- PV: B-fragment slot-matched from V^T (two b64 reads per ht) ----
#pragma unroll
        for (int ht = 0; ht < 4; ++ht) {
            const int h = ht * 16 + c;
            const int sw = (h & 7) << 4;
            const char* vr = vb + h * 128;
            union { s16x4 q[2]; short8 s; } vfu;
            vfu.q[0] = *(const s16x4*)(vr + ((wk * 64 + g * 8) ^ sw));       // keys 4g..4g+3
            vfu.q[1] = *(const s16x4*)(vr + ((wk * 64 + 32 + g * 8) ^ sw));  // keys 16+4g..+3
            vals[ht] = MFMA16(pau.s, vfu.s, vals[ht]);
        }

        __syncthreads();  // stage(it+1) drained; buffer swap safe
        { char* t0 = b0; b0 = b1; b1 = t0; }
        bcur0 = bn0; bcur1 = bn1;
    }

    // ---- denominator: sum the 4 g-lanes of q-row c ----
    dsum += __shfl_xor(dsum, 16);
    dsum += __shfl_xor(dsum, 32);

    // ---- cross-wk combine; rv (16.6KB) aliases the stage buffers (loop done) ----
    float* rv = (float*)smem;  // [2 wk][32 q][65]
#pragma unroll
    for (int ht = 0; ht < 4; ++ht)
#pragma unroll
        for (int r = 0; r < 4; ++r)
            rv[(wk * 32 + wq * 16 + g * 4 + r) * 65 + ht * 16 + c] = vals[ht][r];
    if (g == 0)
        rv[(wk * 32 + wq * 16 + c) * 65 + 64] = dsum;
    __syncthreads();

    const int h = tid & 63;
    for (int qq = tid >> 6; qq < QB2; qq += 4) {
        const float v = rv[qq * 65 + h] + rv[(32 + qq) * 65 + h];
        pv[((size_t)bid * QB2 + qq) * H + h] = v;
        if (h == 0)
            pd[(size_t)bid * QB2 + qq] = rv[qq * 65 + 64] + rv[(32 + qq) * 65 + 64];
    }
}

// -------- kernel 3: combine key-split partials, divide, ELU --------
__global__ __launch_bounds__(256) void reduce_kernel(const float* __restrict__ pv,
                                                     const float* __restrict__ pd,
                                                     float* __restrict__ out) {
    const int i = blockIdx.x * 256 + threadIdx.x;  // N*H
    const int q = i >> 6, h = i & 63;
    const int qc = q >> 5, qi = q & 31;
    float v = 0.f, d = 0.f;
#pragma unroll
    for (int ks = 0; ks < KSPLIT; ++ks) {
        const size_t row = (size_t)(qc * KSPLIT + ks) * QB2 + qi;
        v += pv[row * H + h];
        d += pd[row];
    }
    const float x = v / (d + 1e-19f);
    out[i] = x > 0.f ? x : expm1f(x);
}

extern "C" void kernel_launch(void* const* d_in, const int* in_sizes, int n_in,
                              void* d_out, int out_size, void* d_ws, size_t ws_size,
                              hipStream_t stream) {
    const float* seq  = (const float*)d_in[0];
    const float* bias = (const float*)d_in[1];
    const float* W1   = (const float*)d_in[2];
    const float* W2   = (const float*)d_in[3];
    // d_in[4] = bias_zero (zeros) -- folded out
    float* out = (float*)d_out;

    unsigned short* Qb  = (unsigned short*)d_ws;   // 1 MB (also V)
    unsigned short* Kb  = Qb + (size_t)N * H;      // 1 MB
    unsigned short* QT  = Kb + (size_t)N * H;      // 1 MB (V^T)
    unsigned short* W1T = QT + (size_t)N * H;      // 16 KB
    unsigned short* W2T = W1T + (size_t)H * FIN;   // 16 KB
    float* pv = (float*)(W2T + (size_t)H * FIN);   // 1024*32*64 f32 = 8 MB
    float* pd = pv + (size_t)(N / QB2) * KSPLIT * QB2 * H;  // 128 KB

    wprep_kernel<<<32, 256, 0, stream>>>(W1, W2, W1T, W2T);
    proj_kernel<<<N / 32, 256, 0, stream>>>(seq, W1T, W2T, Qb, Kb, QT);
    flash_kernel<<<(N / QB2) * KSPLIT, 256, 0, stream>>>(Qb, Kb, QT, bias, pv, pd);
    reduce_kernel<<<(N * H) / 256, 256, 0, stream>>>(pv, pd, out);
}